// Round 16
// baseline (59.280 us; speedup 1.0000x reference)
//
#include <hip/hip_runtime.h>

#define LN_EPS 1e-5f

// ---------------------------------------------------------------------------
// Index algebra (verified passing rounds 2-15):
//   F[which][b][g][cc][cs*64+d] = P_{which}[b, s_i, h_i*64+d] + bias
//     s_i = (cc<2 ? 240+8*cc : 8*(cc-2)) + cs,  h_i = g*2 + (cc>>1)
//   Dt[b][gq][gk][cc][cs] = dot64(Fq, Fk) / 8
//   SFK[b][c][d] = 32 * sum_gv FK[b][gv][c>>3][(c&7)*64+d]
//   attn: per (q,k) softmax over 32 c of (vq&vk ? Dt : 0); masked -> 1/32.
//   A[c] = sum_k attn;  ctx[b,q,h*64+d] = sum_c A[c]*SFK[b][c][d].
//   attn_out == 1.0 everywhere.
// MEASURED LEDGER: kG4LN(r9) 8.8 (structural floor ~7.4 for row-complete
//   blocks: traffic x chip-fraction invariant) | kAttn 6.5 | kAo_at ~3 |
//   kC ~1 | fixed ~6.3 | gap ~1.5-2/boundary.
// r15 LESSON: 1024-thr 16-wave blocks with 6 barriers regress (idle waves
//   at barriers); keep 512-thr 8-wave blocks.
// r16: kAGL = kAttn+kG4LN+LN in ONE kernel. Block = 4 rows; wave w = head h
//   computes attn for 4 q's -> ctx slice into LDS Cl; barrier; r9 GEMM body.
//   Kills 1 gap + kAttn launch + 2MB ctx round-trip.
// ---------------------------------------------------------------------------

#define FMA4(a, s, v) { (a).x += (s)*(v).x; (a).y += (s)*(v).y; \
                        (a).z += (s)*(v).z; (a).w += (s)*(v).w; }

__device__ __forceinline__ bool sniff_mask_bytes(const unsigned int* m) {
    unsigned int acc = 0;
#pragma unroll
    for (int i = 0; i < 16; ++i) acc |= m[i];
    return acc > 1u;
}

// kAo_at: projection, outer-product split-K, atomicAdd into zeroed F.
// 64 blocks = which(2) x b(2) x mc(16); 512 thr = one output column n each.
__global__ __launch_bounds__(512) void kAo_at(
    const float* __restrict__ Qin, const float* __restrict__ Kin,
    const float* __restrict__ WQ, const float* __restrict__ bQ,
    const float* __restrict__ WK, const float* __restrict__ bK,
    float* __restrict__ F)
{
    __shared__ float Xs[32][36];
    int bx = blockIdx.x;
    int mc = bx & 15, b = (bx >> 4) & 1, which = bx >> 5;
    int m0 = mc * 32;
    int t = threadIdx.x;

    const float* In = which ? Kin : Qin;
    const float* W  = which ? WK  : WQ;

#pragma unroll
    for (int i = 0; i < 2; ++i) {
        int idx = i * 512 + t;
        int fr = idx >> 5, mm = idx & 31;
        int cc = fr >> 3, cs = fr & 7;
        int srow = (cc < 2) ? (240 + 8 * cc + cs) : (8 * (cc - 2) + cs);
        Xs[mm][fr] = In[(b * 256 + srow) * 512 + m0 + mm];
    }
    __syncthreads();

    int h_i = t >> 6, g = t >> 7;
    int cc0 = (h_i & 1) * 2;
    float acc[16];
#pragma unroll
    for (int j = 0; j < 16; ++j) acc[j] = 0.f;

    const float* wp = W + t;
#pragma unroll 4
    for (int mm = 0; mm < 32; ++mm) {
        float w = wp[(m0 + mm) * 512];
        const float4* xp = (const float4*)&Xs[mm][cc0 * 8];
        float4 x0 = xp[0], x1 = xp[1], x2 = xp[2], x3 = xp[3];
        acc[0]  += x0.x * w; acc[1]  += x0.y * w; acc[2]  += x0.z * w; acc[3]  += x0.w * w;
        acc[4]  += x1.x * w; acc[5]  += x1.y * w; acc[6]  += x1.z * w; acc[7]  += x1.w * w;
        acc[8]  += x2.x * w; acc[9]  += x2.y * w; acc[10] += x2.z * w; acc[11] += x2.w * w;
        acc[12] += x3.x * w; acc[13] += x3.y * w; acc[14] += x3.z * w; acc[15] += x3.w * w;
    }

    float bb = (mc == 0) ? (which ? bK[t] : bQ[t]) : 0.f;
    int d = t & 63;
    int base = ((which * 2 + b) * 4 + g) * 4;
#pragma unroll
    for (int j = 0; j < 16; ++j) {
        int ccj = cc0 + (j >> 3), cs = j & 7;
        atomicAdd(&F[(base + ccj) * 512 + cs * 64 + d], acc[j] + bb);
    }
}

// kC: Dt (8-lane dots + shfl) and SFK (pre-scaled x32).  48 blocks x 256 thr.
__global__ void kC_dtab_sfk(const float* __restrict__ F, float* __restrict__ Dt,
                            float* __restrict__ SFK) {
    int slot = blockIdx.x * 256 + threadIdx.x;
    if (slot < 8192) {
        int part = slot & 7, e = slot >> 3;
        int cs = e & 7, cc = (e >> 3) & 3, gk = (e >> 5) & 3,
            gq = (e >> 7) & 3, b = (e >> 9) & 1;
        const float* fq = F + ((b * 4 + gq) * 4 + cc) * 512 + cs * 64 + part * 8;
        const float* fk = F + (((2 + b) * 4 + gk) * 4 + cc) * 512 + cs * 64 + part * 8;
        float a = 0.f;
#pragma unroll
        for (int u = 0; u < 8; ++u) a += fq[u] * fk[u];
        a += __shfl_xor(a, 1);
        a += __shfl_xor(a, 2);
        a += __shfl_xor(a, 4);
        if (part == 0) Dt[e] = a * 0.125f;
    } else {
        int e = slot - 8192;
        int d = e & 63, c = (e >> 6) & 31, b = e >> 11;
        float a = 0.f;
#pragma unroll
        for (int gv = 0; gv < 4; ++gv)
            a += F[(((2 + b) * 4 + gv) * 4 + (c >> 3)) * 512 + (c & 7) * 64 + d];
        SFK[e] = 32.f * a;
    }
}

// kAGL: attention + Wo GEMM + bias + residual + LayerNorm, one kernel.
// 128 blocks x 512 thr; block = rows r0..r0+3 (b = r0>>8, q = qb*4+j).
// Phase 1: wave w = head h computes attn for j=0..3 -> Cl[j][h*64+l].
// Phase 2 (verbatim r9 kG4LN body): outer-product Wo GEMM from Cl, two-pass
// LDS reduce with bias+residual, then in-block LayerNorm.
__global__ __launch_bounds__(512) void kAGL(
    const float* __restrict__ Dt, const void* __restrict__ maskp,
    const float* __restrict__ SFK,
    const float* __restrict__ Wo, const float* __restrict__ bo,
    const float* __restrict__ Qin, const float* __restrict__ gamma,
    const float* __restrict__ beta, float* __restrict__ out,
    float* __restrict__ attnp, int fill)
{
    __shared__ float  Cl[4][512];
    __shared__ float4 red4[8][4][64];
    __shared__ float  red2[8][2];
    __shared__ float  aws[8][32];

    int t = threadIdx.x, blk = blockIdx.x;
    int r0 = blk * 4;
    int b = r0 >> 8, qb = blk & 63;
    int w = t >> 6, l = t & 63;

    if (fill) {
        float4 one = make_float4(1.f, 1.f, 1.f, 1.f);
#pragma unroll
        for (int i = 0; i < 4; ++i)
            ((float4*)attnp)[i * 65536 + blk * 512 + t] = one;
    }

    // ---- Phase 1: attention.  h = w; 2 lanes per k, 16 c each; 4 q's.
    int h = w;
    int half = l & 1, klo = l >> 1;
    int ak = klo & 3;
    bool up_k = (klo & 4) == 0;
    bool mbytes = sniff_mask_bytes((const unsigned int*)maskp);
    const float* S = SFK + b * 2048;

    for (int j = 0; j < 4; ++j) {
        int q = qb * 4 + j;
        int g_q = q & 3;
        int i_q = h * 32 + (q >> 3);
        bool up_q = (q & 4) == 0;

        float sq[16];
        const float* Db = Dt + ((b * 4 + g_q) * 4 + ak) * 32 + half * 16;
#pragma unroll
        for (int jj = 0; jj < 16; ++jj) {
            int cc = half * 2 + (jj >> 3);
            int row = g_q * 64 + 30 + cc;
            bool vq = up_q ? (i_q >= 256 - row) : (i_q <= 255 - row);
            sq[jj] = vq ? Db[jj] : 0.f;
        }

        float A[16];
#pragma unroll
        for (int jj = 0; jj < 16; ++jj) A[jj] = 0.f;

        int qrow = (b * 256 + q) * 256;
        for (int r = 0; r < 8; ++r) {
            int k = r * 32 + klo;
            bool masked = mbytes ? (((const unsigned char*)maskp)[qrow + k] != 0)
                                 : (((const int*)maskp)[qrow + k] != 0);
            if (masked) {
#pragma unroll
                for (int jj = 0; jj < 16; ++jj) A[jj] += 0.03125f;
                continue;
            }
            int i_k = h * 32 + (k >> 3);
            float s[16];
            float mx = -1e30f;
#pragma unroll
            for (int jj = 0; jj < 16; ++jj) {
                int cc = half * 2 + (jj >> 3);
                int row = ak * 64 + 30 + cc;
                bool vk = up_k ? (i_k >= 256 - row) : (i_k <= 255 - row);
                s[jj] = vk ? sq[jj] : 0.f;
                mx = fmaxf(mx, s[jj]);
            }
            mx = fmaxf(mx, __shfl_xor(mx, 1));
            float den = 0.f;
#pragma unroll
            for (int jj = 0; jj < 16; ++jj) { s[jj] = __expf(s[jj] - mx); den += s[jj]; }
            den += __shfl_xor(den, 1);
            float inv = 1.f / den;
#pragma unroll
            for (int jj = 0; jj < 16; ++jj) A[jj] += s[jj] * inv;
        }

#pragma unroll
        for (int off = 2; off < 64; off <<= 1) {
#pragma unroll
            for (int jj = 0; jj < 16; ++jj) A[jj] += __shfl_xor(A[jj], off);
        }

        if (l < 2) {
#pragma unroll
            for (int jj = 0; jj < 16; ++jj) aws[w][l * 16 + jj] = A[jj];
        }
        float acc = 0.f;
#pragma unroll
        for (int c = 0; c < 32; ++c) acc += aws[w][c] * S[c * 64 + l];
        Cl[j][h * 64 + l] = acc;
    }
    __syncthreads();

    // ---- Phase 2: Wo GEMM + bias + residual + LN (r9 kG4LN body).
    const float4* WoV = (const float4*)Wo;
    const float4* pA = WoV + (size_t)(w * 64) * 128 + l;
    const float4* pB = pA + 64;
    float4 a0A = {0,0,0,0}, a1A = {0,0,0,0}, a2A = {0,0,0,0}, a3A = {0,0,0,0};
    float4 a0B = {0,0,0,0}, a1B = {0,0,0,0}, a2B = {0,0,0,0}, a3B = {0,0,0,0};
    int m0 = w * 64;
    float4 wA = pA[0], wB = pB[0];
#pragma unroll 4
    for (int mm = 0; mm < 63; ++mm) {
        float4 nA = pA[(mm + 1) * 128];
        float4 nB = pB[(mm + 1) * 128];
        float s0 = Cl[0][m0 + mm], s1 = Cl[1][m0 + mm];
        float s2 = Cl[2][m0 + mm], s3 = Cl[3][m0 + mm];
        FMA4(a0A, s0, wA); FMA4(a1A, s1, wA); FMA4(a2A, s2, wA); FMA4(a3A, s3, wA);
        FMA4(a0B, s0, wB); FMA4(a1B, s1, wB); FMA4(a2B, s2, wB); FMA4(a3B, s3, wB);
        wA = nA; wB = nB;
    }
    {
        float s0 = Cl[0][m0 + 63], s1 = Cl[1][m0 + 63];
        float s2 = Cl[2][m0 + 63], s3 = Cl[3][m0 + 63];
        FMA4(a0A, s0, wA); FMA4(a1A, s1, wA); FMA4(a2A, s2, wA); FMA4(a3A, s3, wA);
        FMA4(a0B, s0, wB); FMA4(a1B, s1, wB); FMA4(a2B, s2, wB); FMA4(a3B, s3, wB);
    }

    red4[w][0][l] = a0A; red4[w][1][l] = a1A; red4[w][2][l] = a2A; red4[w][3][l] = a3A;
    __syncthreads();
    if (t < 256) {
        int r = t >> 6, c4 = t & 63;
        float4 s = red4[0][r][c4];
#pragma unroll
        for (int w2 = 1; w2 < 8; ++w2) {
            float4 v = red4[w2][r][c4];
            s.x += v.x; s.y += v.y; s.z += v.z; s.w += v.w;
        }
        float4 bb = ((const float4*)bo)[c4];
        float4 qq = ((const float4*)Qin)[(r0 + r) * 128 + c4];
        s.x += bb.x + qq.x; s.y += bb.y + qq.y;
        s.z += bb.z + qq.z; s.w += bb.w + qq.w;
        *(float4*)&Cl[r][c4 * 4] = s;
    }
    __syncthreads();
    red4[w][0][l] = a0B; red4[w][1][l] = a1B; red4[w][2][l] = a2B; red4[w][3][l] = a3B;
    __syncthreads();
    if (t < 256) {
        int r = t >> 6, c4 = t & 63;
        float4 s = red4[0][r][c4];
#pragma unroll
        for (int w2 = 1; w2 < 8; ++w2) {
            float4 v = red4[w2][r][c4];
            s.x += v.x; s.y += v.y; s.z += v.z; s.w += v.w;
        }
        float4 bb = ((const float4*)bo)[64 + c4];
        float4 qq = ((const float4*)Qin)[(r0 + r) * 128 + 64 + c4];
        s.x += bb.x + qq.x; s.y += bb.y + qq.y;
        s.z += bb.z + qq.z; s.w += bb.w + qq.w;
        *(float4*)&Cl[r][256 + c4 * 4] = s;
    }
    __syncthreads();

    int r = t >> 7, c = t & 127;
    float v0 = Cl[r][c], v1 = Cl[r][c + 128], v2 = Cl[r][c + 256], v3 = Cl[r][c + 384];
    float s1 = v0 + v1 + v2 + v3;
    float s2 = v0 * v0 + v1 * v1 + v2 * v2 + v3 * v3;
#pragma unroll
    for (int off = 1; off < 64; off <<= 1) {
        s1 += __shfl_xor(s1, off);
        s2 += __shfl_xor(s2, off);
    }
    if (l == 0) { red2[w][0] = s1; red2[w][1] = s2; }
    __syncthreads();
    float tot1 = red2[2 * r][0] + red2[2 * r + 1][0];
    float tot2 = red2[2 * r][1] + red2[2 * r + 1][1];
    float mu = tot1 * (1.f / 512.f);
    float var = tot2 * (1.f / 512.f) - mu * mu;
    float rs = rsqrtf(var + LN_EPS);
    float* op = out + (r0 + r) * 512;
    op[c]       = (v0 - mu) * rs * gamma[c]       + beta[c];
    op[c + 128] = (v1 - mu) * rs * gamma[c + 128] + beta[c + 128];
    op[c + 256] = (v2 - mu) * rs * gamma[c + 256] + beta[c + 256];
    op[c + 384] = (v3 - mu) * rs * gamma[c + 384] + beta[c + 384];
}

// plan-B only: restore attn_out region (which hosted scratch) to 1.0
__global__ void k5_fill(float* __restrict__ p, int n) {
    int i = (blockIdx.x * 256 + threadIdx.x) * 4;
    float4 one = make_float4(1.f, 1.f, 1.f, 1.f);
    for (; i < n; i += gridDim.x * 256 * 4) *(float4*)(p + i) = one;
}

extern "C" void kernel_launch(void* const* d_in, const int* in_sizes, int n_in,
                              void* d_out, int out_size, void* d_ws, size_t ws_size,
                              hipStream_t stream) {
    (void)in_sizes; (void)n_in; (void)out_size;
    const float* Qin  = (const float*)d_in[0];
    const float* Kin  = (const float*)d_in[1];
    const void*  mask = d_in[3];
    const float* WQ   = (const float*)d_in[4];
    const float* bQ   = (const float*)d_in[5];
    const float* WK   = (const float*)d_in[6];
    const float* bK   = (const float*)d_in[7];
    const float* Wo   = (const float*)d_in[10];
    const float* bo   = (const float*)d_in[11];
    const float* gamma= (const float*)d_in[12];
    const float* beta = (const float*)d_in[13];

    float* out   = (float*)d_out;
    float* attnp = out + 262144;                  // 1,048,576 floats (output 1)

    const size_t NEED = 37888ull * sizeof(float);
    int fill;
    float *F, *Dt, *SFK;
    if (ws_size >= NEED) {                        // plan A
        float* ws = (float*)d_ws;
        F   = ws;                                 // 32768
        Dt  = ws + 32768;                         // 1024
        SFK = ws + 33792;                         // 4096
        fill = 1;
    } else {                                      // plan B (inside attn_out)
        F   = attnp + 524288;
        Dt  = attnp + 557056;
        SFK = attnp + 558080;
        fill = 0;
    }

    hipMemsetAsync(F, 0, 32768 * sizeof(float), stream);
    kAo_at     <<<dim3(64),  dim3(512), 0, stream>>>(Qin, Kin, WQ, bQ, WK, bK, F);
    kC_dtab_sfk<<<dim3(48),  dim3(256), 0, stream>>>(F, Dt, SFK);
    kAGL       <<<dim3(128), dim3(512), 0, stream>>>(Dt, mask, SFK, Wo, bo, Qin,
                                                     gamma, beta, out, attnp, fill);
    if (!fill) k5_fill<<<dim3(256), dim3(256), 0, stream>>>(attnp, 1048576);
}

// Round 17
// 42.894 us; speedup vs baseline: 1.3820x; 1.3820x over previous
//
#include <hip/hip_runtime.h>

#define LN_EPS 1e-5f

// ---------------------------------------------------------------------------
// Index algebra (verified passing rounds 2-16):
//   F[which][b][g][cc][cs*64+d] = P_{which}[b, s_i, h_i*64+d] + bias
//     s_i = (cc<2 ? 240+8*cc : 8*(cc-2)) + cs,  h_i = g*2 + (cc>>1)
//   Dt[b][gq][gk][cc][cs] = dot64(Fq, Fk) / 8
//   SFK[b][c][d] = 32 * sum_gv FK[b][gv][c>>3][(c&7)*64+d]
//   attn: per (q,k) softmax over 32 c of (vq&vk ? Dt : 0); masked -> 1/32.
//   A[c] = sum_k attn;  ctx[b,q,h*64+d] = sum_c A[c]*SFK[b][c][d].
//   attn_out == 1.0 everywhere.
// MEASURED LEDGER (r10-r16): kG4LN(r9)=8.8 | kAttn=6.5 | kAo_at~3 | kC~1 |
//   fixed~6.3 | boundary~2.2.  FUSION LESSONS: grid-wide coop sync = 200us/
//   sync (r4); per-block table replication = L2 poison (r14); 16-wave
//   blocks idle at barriers (r15); fusing phases with mismatched
//   concurrency (1024-blk attn into 128-blk GEMM) stretches the narrow
//   phase ~4x (r16).  This round: bank the measured-best 4-kernel config.
// ---------------------------------------------------------------------------

#define FMA4(a, s, v) { (a).x += (s)*(v).x; (a).y += (s)*(v).y; \
                        (a).z += (s)*(v).z; (a).w += (s)*(v).w; }

__device__ __forceinline__ bool sniff_mask_bytes(const unsigned int* m) {
    unsigned int acc = 0;
#pragma unroll
    for (int i = 0; i < 16; ++i) acc |= m[i];
    return acc > 1u;
}

// kAo_at: projection, outer-product split-K, atomicAdd into zeroed F.
// 64 blocks = which(2) x b(2) x mc(16); 512 thr = one output column n each.
__global__ __launch_bounds__(512) void kAo_at(
    const float* __restrict__ Qin, const float* __restrict__ Kin,
    const float* __restrict__ WQ, const float* __restrict__ bQ,
    const float* __restrict__ WK, const float* __restrict__ bK,
    float* __restrict__ F)
{
    __shared__ float Xs[32][36];
    int bx = blockIdx.x;
    int mc = bx & 15, b = (bx >> 4) & 1, which = bx >> 5;
    int m0 = mc * 32;
    int t = threadIdx.x;

    const float* In = which ? Kin : Qin;
    const float* W  = which ? WK  : WQ;

#pragma unroll
    for (int i = 0; i < 2; ++i) {
        int idx = i * 512 + t;
        int fr = idx >> 5, mm = idx & 31;
        int cc = fr >> 3, cs = fr & 7;
        int srow = (cc < 2) ? (240 + 8 * cc + cs) : (8 * (cc - 2) + cs);
        Xs[mm][fr] = In[(b * 256 + srow) * 512 + m0 + mm];
    }
    __syncthreads();

    int h_i = t >> 6, g = t >> 7;
    int cc0 = (h_i & 1) * 2;
    float acc[16];
#pragma unroll
    for (int j = 0; j < 16; ++j) acc[j] = 0.f;

    const float* wp = W + t;
#pragma unroll 4
    for (int mm = 0; mm < 32; ++mm) {
        float w = wp[(m0 + mm) * 512];
        const float4* xp = (const float4*)&Xs[mm][cc0 * 8];
        float4 x0 = xp[0], x1 = xp[1], x2 = xp[2], x3 = xp[3];
        acc[0]  += x0.x * w; acc[1]  += x0.y * w; acc[2]  += x0.z * w; acc[3]  += x0.w * w;
        acc[4]  += x1.x * w; acc[5]  += x1.y * w; acc[6]  += x1.z * w; acc[7]  += x1.w * w;
        acc[8]  += x2.x * w; acc[9]  += x2.y * w; acc[10] += x2.z * w; acc[11] += x2.w * w;
        acc[12] += x3.x * w; acc[13] += x3.y * w; acc[14] += x3.z * w; acc[15] += x3.w * w;
    }

    float bb = (mc == 0) ? (which ? bK[t] : bQ[t]) : 0.f;
    int d = t & 63;
    int base = ((which * 2 + b) * 4 + g) * 4;
#pragma unroll
    for (int j = 0; j < 16; ++j) {
        int ccj = cc0 + (j >> 3), cs = j & 7;
        atomicAdd(&F[(base + ccj) * 512 + cs * 64 + d], acc[j] + bb);
    }
}

// kC: Dt (8-lane dots + shfl) and SFK (pre-scaled x32).  48 blocks x 256 thr.
__global__ void kC_dtab_sfk(const float* __restrict__ F, float* __restrict__ Dt,
                            float* __restrict__ SFK) {
    int slot = blockIdx.x * 256 + threadIdx.x;
    if (slot < 8192) {
        int part = slot & 7, e = slot >> 3;
        int cs = e & 7, cc = (e >> 3) & 3, gk = (e >> 5) & 3,
            gq = (e >> 7) & 3, b = (e >> 9) & 1;
        const float* fq = F + ((b * 4 + gq) * 4 + cc) * 512 + cs * 64 + part * 8;
        const float* fk = F + (((2 + b) * 4 + gk) * 4 + cc) * 512 + cs * 64 + part * 8;
        float a = 0.f;
#pragma unroll
        for (int u = 0; u < 8; ++u) a += fq[u] * fk[u];
        a += __shfl_xor(a, 1);
        a += __shfl_xor(a, 2);
        a += __shfl_xor(a, 4);
        if (part == 0) Dt[e] = a * 0.125f;
    } else {
        int e = slot - 8192;
        int d = e & 63, c = (e >> 6) & 31, b = e >> 11;
        float a = 0.f;
#pragma unroll
        for (int gv = 0; gv < 4; ++gv)
            a += F[(((2 + b) * 4 + gv) * 4 + (c >> 3)) * 512 + (c & 7) * 64 + d];
        SFK[e] = 32.f * a;
    }
}

// kAttn: 1024 blocks x 256 thr.  Wave per (h,q); 2 lanes per k, 16 c each.
// (r13 version — Dt/SFK from L2, measured 6.5us.)
__global__ void kAttn(const float* __restrict__ Dt, const void* __restrict__ maskp,
                      const float* __restrict__ SFK, float* __restrict__ ctx,
                      float* __restrict__ attnp, int fill) {
    __shared__ float aws[4][32];
    int vb = blockIdx.x, t = threadIdx.x;
    if (fill) ((float4*)attnp)[vb * 256 + t] = make_float4(1.f, 1.f, 1.f, 1.f);
    int qb = vb & 63, h = (vb >> 6) & 7, b = vb >> 9;
    int wave = t >> 6, l = t & 63;
    int q = qb * 4 + wave;
    int half = l & 1, klo = l >> 1;
    int g_q = q & 3;
    int i_q = h * 32 + (q >> 3);
    bool up_q = (q & 4) == 0;
    int ak = klo & 3;
    bool up_k = (klo & 4) == 0;

    bool mbytes = sniff_mask_bytes((const unsigned int*)maskp);

    float sq[16];
    const float* Db = Dt + ((b * 4 + g_q) * 4 + ak) * 32 + half * 16;
#pragma unroll
    for (int j = 0; j < 16; ++j) {
        int cc = half * 2 + (j >> 3);
        int row = g_q * 64 + 30 + cc;
        bool vq = up_q ? (i_q >= 256 - row) : (i_q <= 255 - row);
        sq[j] = vq ? Db[j] : 0.f;
    }

    float A[16];
#pragma unroll
    for (int j = 0; j < 16; ++j) A[j] = 0.f;

    int qrow = (b * 256 + q) * 256;
    for (int r = 0; r < 8; ++r) {
        int k = r * 32 + klo;
        bool masked = mbytes ? (((const unsigned char*)maskp)[qrow + k] != 0)
                             : (((const int*)maskp)[qrow + k] != 0);
        if (masked) {
#pragma unroll
            for (int j = 0; j < 16; ++j) A[j] += 0.03125f;
            continue;
        }
        int i_k = h * 32 + (k >> 3);
        float s[16];
        float mx = -1e30f;
#pragma unroll
        for (int j = 0; j < 16; ++j) {
            int cc = half * 2 + (j >> 3);
            int row = ak * 64 + 30 + cc;
            bool vk = up_k ? (i_k >= 256 - row) : (i_k <= 255 - row);
            s[j] = vk ? sq[j] : 0.f;
            mx = fmaxf(mx, s[j]);
        }
        mx = fmaxf(mx, __shfl_xor(mx, 1));
        float den = 0.f;
#pragma unroll
        for (int j = 0; j < 16; ++j) { s[j] = __expf(s[j] - mx); den += s[j]; }
        den += __shfl_xor(den, 1);
        float inv = 1.f / den;
#pragma unroll
        for (int j = 0; j < 16; ++j) A[j] += s[j] * inv;
    }

#pragma unroll
    for (int off = 2; off < 64; off <<= 1) {
#pragma unroll
        for (int j = 0; j < 16; ++j) A[j] += __shfl_xor(A[j], off);
    }

    float* aw = aws[wave];
    if (l < 2) {
#pragma unroll
        for (int j = 0; j < 16; ++j) aw[l * 16 + j] = A[j];
    }
    float acc = 0.f;
    const float* S = SFK + b * 2048;
#pragma unroll
    for (int c = 0; c < 32; ++c) acc += aw[c] * S[c * 64 + l];
    ctx[(b * 256 + q) * 512 + h * 64 + l] = acc;
}

// kG4LN: outer-product Wo GEMM + bias + residual + LayerNorm, fused.
// 128 blocks x 512 thr; block = 4 output rows.  (r9 version, 8.8us warm.)
__global__ __launch_bounds__(512) void kG4LN(
    const float* __restrict__ ctx, const float* __restrict__ Wo,
    const float* __restrict__ bo, const float* __restrict__ Qin,
    const float* __restrict__ gamma, const float* __restrict__ beta,
    float* __restrict__ out)
{
    __shared__ float  Cl[4][512];
    __shared__ float4 red4[8][4][64];
    __shared__ float  red2[8][2];

    int t = threadIdx.x, r0 = blockIdx.x * 4;
    int w = t >> 6, l = t & 63;

    ((float4*)Cl)[t] = ((const float4*)&ctx[r0 * 512])[t];
    __syncthreads();

    const float4* WoV = (const float4*)Wo;
    const float4* pA = WoV + (size_t)(w * 64) * 128 + l;
    const float4* pB = pA + 64;
    float4 a0A = {0,0,0,0}, a1A = {0,0,0,0}, a2A = {0,0,0,0}, a3A = {0,0,0,0};
    float4 a0B = {0,0,0,0}, a1B = {0,0,0,0}, a2B = {0,0,0,0}, a3B = {0,0,0,0};
    int m0 = w * 64;
    float4 wA = pA[0], wB = pB[0];
#pragma unroll 4
    for (int mm = 0; mm < 63; ++mm) {
        float4 nA = pA[(mm + 1) * 128];
        float4 nB = pB[(mm + 1) * 128];
        float s0 = Cl[0][m0 + mm], s1 = Cl[1][m0 + mm];
        float s2 = Cl[2][m0 + mm], s3 = Cl[3][m0 + mm];
        FMA4(a0A, s0, wA); FMA4(a1A, s1, wA); FMA4(a2A, s2, wA); FMA4(a3A, s3, wA);
        FMA4(a0B, s0, wB); FMA4(a1B, s1, wB); FMA4(a2B, s2, wB); FMA4(a3B, s3, wB);
        wA = nA; wB = nB;
    }
    {
        float s0 = Cl[0][m0 + 63], s1 = Cl[1][m0 + 63];
        float s2 = Cl[2][m0 + 63], s3 = Cl[3][m0 + 63];
        FMA4(a0A, s0, wA); FMA4(a1A, s1, wA); FMA4(a2A, s2, wA); FMA4(a3A, s3, wA);
        FMA4(a0B, s0, wB); FMA4(a1B, s1, wB); FMA4(a2B, s2, wB); FMA4(a3B, s3, wB);
    }

    red4[w][0][l] = a0A; red4[w][1][l] = a1A; red4[w][2][l] = a2A; red4[w][3][l] = a3A;
    __syncthreads();
    if (t < 256) {
        int r = t >> 6, c4 = t & 63;
        float4 s = red4[0][r][c4];
#pragma unroll
        for (int w2 = 1; w2 < 8; ++w2) {
            float4 v = red4[w2][r][c4];
            s.x += v.x; s.y += v.y; s.z += v.z; s.w += v.w;
        }
        float4 bb = ((const float4*)bo)[c4];
        float4 qq = ((const float4*)Qin)[(r0 + r) * 128 + c4];
        s.x += bb.x + qq.x; s.y += bb.y + qq.y;
        s.z += bb.z + qq.z; s.w += bb.w + qq.w;
        *(float4*)&Cl[r][c4 * 4] = s;
    }
    __syncthreads();
    red4[w][0][l] = a0B; red4[w][1][l] = a1B; red4[w][2][l] = a2B; red4[w][3][l] = a3B;
    __syncthreads();
    if (t < 256) {
        int r = t >> 6, c4 = t & 63;
        float4 s = red4[0][r][c4];
#pragma unroll
        for (int w2 = 1; w2 < 8; ++w2) {
            float4 v = red4[w2][r][c4];
            s.x += v.x; s.y += v.y; s.z += v.z; s.w += v.w;
        }
        float4 bb = ((const float4*)bo)[64 + c4];
        float4 qq = ((const float4*)Qin)[(r0 + r) * 128 + 64 + c4];
        s.x += bb.x + qq.x; s.y += bb.y + qq.y;
        s.z += bb.z + qq.z; s.w += bb.w + qq.w;
        *(float4*)&Cl[r][256 + c4 * 4] = s;
    }
    __syncthreads();

    int r = t >> 7, c = t & 127;
    float v0 = Cl[r][c], v1 = Cl[r][c + 128], v2 = Cl[r][c + 256], v3 = Cl[r][c + 384];
    float s1 = v0 + v1 + v2 + v3;
    float s2 = v0 * v0 + v1 * v1 + v2 * v2 + v3 * v3;
#pragma unroll
    for (int off = 1; off < 64; off <<= 1) {
        s1 += __shfl_xor(s1, off);
        s2 += __shfl_xor(s2, off);
    }
    if (l == 0) { red2[w][0] = s1; red2[w][1] = s2; }
    __syncthreads();
    float tot1 = red2[2 * r][0] + red2[2 * r + 1][0];
    float tot2 = red2[2 * r][1] + red2[2 * r + 1][1];
    float mu = tot1 * (1.f / 512.f);
    float var = tot2 * (1.f / 512.f) - mu * mu;
    float rs = rsqrtf(var + LN_EPS);
    float* op = out + (r0 + r) * 512;
    op[c]       = (v0 - mu) * rs * gamma[c]       + beta[c];
    op[c + 128] = (v1 - mu) * rs * gamma[c + 128] + beta[c + 128];
    op[c + 256] = (v2 - mu) * rs * gamma[c + 256] + beta[c + 256];
    op[c + 384] = (v3 - mu) * rs * gamma[c + 384] + beta[c + 384];
}

// plan-B only: restore attn_out region (which hosted scratch) to 1.0
__global__ void k5_fill(float* __restrict__ p, int n) {
    int i = (blockIdx.x * 256 + threadIdx.x) * 4;
    float4 one = make_float4(1.f, 1.f, 1.f, 1.f);
    for (; i < n; i += gridDim.x * 256 * 4) *(float4*)(p + i) = one;
}

extern "C" void kernel_launch(void* const* d_in, const int* in_sizes, int n_in,
                              void* d_out, int out_size, void* d_ws, size_t ws_size,
                              hipStream_t stream) {
    (void)in_sizes; (void)n_in; (void)out_size;
    const float* Qin  = (const float*)d_in[0];
    const float* Kin  = (const float*)d_in[1];
    const void*  mask = d_in[3];
    const float* WQ   = (const float*)d_in[4];
    const float* bQ   = (const float*)d_in[5];
    const float* WK   = (const float*)d_in[6];
    const float* bK   = (const float*)d_in[7];
    const float* Wo   = (const float*)d_in[10];
    const float* bo   = (const float*)d_in[11];
    const float* gamma= (const float*)d_in[12];
    const float* beta = (const float*)d_in[13];

    float* out   = (float*)d_out;
    float* attnp = out + 262144;                  // 1,048,576 floats (output 1)

    const size_t NEED = 300032ull * sizeof(float);
    int fill;
    float *F, *Dt, *SFK, *ctx;
    if (ws_size >= NEED) {                        // plan A
        float* ws = (float*)d_ws;
        F   = ws;                                 // 32768
        Dt  = ws + 32768;                         // 1024
        SFK = ws + 33792;                         // 4096
        ctx = ws + 37888;                         // 262144
        fill = 1;
    } else {                                      // plan B (inside attn_out)
        F   = attnp + 524288;
        Dt  = attnp + 557056;
        SFK = attnp + 558080;
        ctx = attnp + 786432;
        fill = 0;
    }

    hipMemsetAsync(F, 0, 32768 * sizeof(float), stream);
    kAo_at     <<<dim3(64),   dim3(512), 0, stream>>>(Qin, Kin, WQ, bQ, WK, bK, F);
    kC_dtab_sfk<<<dim3(48),   dim3(256), 0, stream>>>(F, Dt, SFK);
    kAttn      <<<dim3(1024), dim3(256), 0, stream>>>(Dt, mask, SFK, ctx, attnp, fill);
    kG4LN      <<<dim3(128),  dim3(512), 0, stream>>>(ctx, Wo, bo, Qin, gamma, beta, out);
    if (!fill) k5_fill<<<dim3(256), dim3(256), 0, stream>>>(attnp, 1048576);
}

// Round 18
// 39.619 us; speedup vs baseline: 1.4962x; 1.0827x over previous
//
#include <hip/hip_runtime.h>

#define LN_EPS 1e-5f

// ---------------------------------------------------------------------------
// Index algebra (verified passing rounds 2-17):
//   F[which][b][g][cc][cs*64+d] = P_{which}[b, s_i, h_i*64+d] + bias
//     s_i = (cc<2 ? 240+8*cc : 8*(cc-2)) + cs,  h_i = g*2 + (cc>>1)
//   Dt[b][gq][gk][cc][cs] = dot64(Fq, Fk) / 8
//   SFK[b][c][d] = 32 * sum_gv FK[b][gv][c>>3][(c&7)*64+d]
//   attn: per (q,k) softmax over 32 c of (vq&vk ? Dt : 0); masked -> 1/32.
//   A[c] = sum_k attn;  ctx[b,q,h*64+d] = sum_c A[c]*SFK[b][c][d].
//   attn_out == 1.0 everywhere.
// MEASURED CONFIG RANKING: r13 (kAo,kB,kC,kAttn,kG4LN)=38.7 < r12=39.9 <
//   r17 (memset+atomics)=42.9 < r9=45.1.  Atomic 16-way contention on F
//   cost +4us vs kB.  ~19us of r13's 38.7 is boundaries+fixed overhead.
// r18: fuse kB+kC -> kBC (Dt/SFK computed straight from Ppart, 16-way
//   reduction + bias folded in; F never materialized).  -1 kernel,
//   -1 boundary, +~1.5us of L2-hot loads in a 48-block kernel.
// ---------------------------------------------------------------------------

#define FMA4(a, s, v) { (a).x += (s)*(v).x; (a).y += (s)*(v).y; \
                        (a).z += (s)*(v).z; (a).w += (s)*(v).w; }
#define ADD4(a, v)    { (a).x += (v).x; (a).y += (v).y; \
                        (a).z += (v).z; (a).w += (v).w; }

__device__ __forceinline__ bool sniff_mask_bytes(const unsigned int* m) {
    unsigned int acc = 0;
#pragma unroll
    for (int i = 0; i < 16; ++i) acc |= m[i];
    return acc > 1u;
}

// kAo: projection, outer-product split-K (r13 version, measured-good).
// 64 blocks = which(2) x b(2) x mc(16); 512 thr = one output column n each.
__global__ __launch_bounds__(512) void kAo_proj_part(
    const float* __restrict__ Qin, const float* __restrict__ Kin,
    const float* __restrict__ WQ, const float* __restrict__ WK,
    float* __restrict__ Ppart)
{
    __shared__ float Xs[32][36];
    int bx = blockIdx.x;
    int mc = bx & 15, b = (bx >> 4) & 1, which = bx >> 5;
    int m0 = mc * 32;
    int t = threadIdx.x;

    const float* In = which ? Kin : Qin;
    const float* W  = which ? WK  : WQ;

#pragma unroll
    for (int i = 0; i < 2; ++i) {
        int idx = i * 512 + t;
        int fr = idx >> 5, mm = idx & 31;
        int cc = fr >> 3, cs = fr & 7;
        int srow = (cc < 2) ? (240 + 8 * cc + cs) : (8 * (cc - 2) + cs);
        Xs[mm][fr] = In[(b * 256 + srow) * 512 + m0 + mm];
    }
    __syncthreads();

    int h_i = t >> 6, g = t >> 7;
    int cc0 = (h_i & 1) * 2;
    float acc[16];
#pragma unroll
    for (int j = 0; j < 16; ++j) acc[j] = 0.f;

    const float* wp = W + t;
#pragma unroll 4
    for (int mm = 0; mm < 32; ++mm) {
        float w = wp[(m0 + mm) * 512];
        const float4* xp = (const float4*)&Xs[mm][cc0 * 8];
        float4 x0 = xp[0], x1 = xp[1], x2 = xp[2], x3 = xp[3];
        acc[0]  += x0.x * w; acc[1]  += x0.y * w; acc[2]  += x0.z * w; acc[3]  += x0.w * w;
        acc[4]  += x1.x * w; acc[5]  += x1.y * w; acc[6]  += x1.z * w; acc[7]  += x1.w * w;
        acc[8]  += x2.x * w; acc[9]  += x2.y * w; acc[10] += x2.z * w; acc[11] += x2.w * w;
        acc[12] += x3.x * w; acc[13] += x3.y * w; acc[14] += x3.z * w; acc[15] += x3.w * w;
    }

    int d = t & 63;
    int base = ((which * 2 + b) * 4 + g) * 4;
#pragma unroll
    for (int j = 0; j < 16; ++j) {
        int ccj = cc0 + (j >> 3), cs = j & 7;
        Ppart[mc * 32768 + (base + ccj) * 512 + cs * 64 + d] = acc[j];
    }
}

// kBC: Dt + SFK computed DIRECTLY from Ppart (16-way mc reduction + bias
// folded).  48 blocks x 256 thr, same slot map as old kC.  F never exists.
__global__ void kBC_dtab_sfk(const float* __restrict__ Ppart,
                             const float* __restrict__ bQ, const float* __restrict__ bK,
                             float* __restrict__ Dt, float* __restrict__ SFK) {
    int slot = blockIdx.x * 256 + threadIdx.x;
    if (slot < 8192) {
        int part = slot & 7, e = slot >> 3;
        int cs = e & 7, cc = (e >> 3) & 3, gk = (e >> 5) & 3,
            gq = (e >> 7) & 3, b = (e >> 9) & 1;
        int offq = ((b * 4 + gq) * 4 + cc) * 512 + cs * 64 + part * 8;        // which=0
        int offk = (((2 + b) * 4 + gk) * 4 + cc) * 512 + cs * 64 + part * 8;  // which=1
        float4 q0 = {0,0,0,0}, q1 = {0,0,0,0}, k0 = {0,0,0,0}, k1 = {0,0,0,0};
#pragma unroll
        for (int mc = 0; mc < 16; ++mc) {
            const float4* pq = (const float4*)(Ppart + mc * 32768 + offq);
            const float4* pk = (const float4*)(Ppart + mc * 32768 + offk);
            float4 a0 = pq[0], a1 = pq[1], c0 = pk[0], c1 = pk[1];
            ADD4(q0, a0); ADD4(q1, a1); ADD4(k0, c0); ADD4(k1, c1);
        }
        int nq = (gq * 2 + (cc >> 1)) * 64 + part * 8;
        int nk = (gk * 2 + (cc >> 1)) * 64 + part * 8;
        const float4* bq4 = (const float4*)(bQ + nq);
        const float4* bk4 = (const float4*)(bK + nk);
        float4 bqa = bq4[0], bqb = bq4[1], bka = bk4[0], bkb = bk4[1];
        ADD4(q0, bqa); ADD4(q1, bqb); ADD4(k0, bka); ADD4(k1, bkb);
        float a = q0.x * k0.x + q0.y * k0.y + q0.z * k0.z + q0.w * k0.w
                + q1.x * k1.x + q1.y * k1.y + q1.z * k1.z + q1.w * k1.w;
        a += __shfl_xor(a, 1);
        a += __shfl_xor(a, 2);
        a += __shfl_xor(a, 4);
        if (part == 0) Dt[e] = a * 0.125f;
    } else {
        int e = slot - 8192;
        int d = e & 63, c = (e >> 6) & 31, b = e >> 11;
        int cc = c >> 3, o = (c & 7) * 64 + d;
        float a = 0.f;
#pragma unroll
        for (int gv = 0; gv < 4; ++gv) {
            int off = (((2 + b) * 4 + gv) * 4 + cc) * 512 + o;
            float s = bK[(gv * 2 + (cc >> 1)) * 64 + d];
#pragma unroll
            for (int mc = 0; mc < 16; ++mc) s += Ppart[mc * 32768 + off];
            a += s;
        }
        SFK[e] = 32.f * a;
    }
}

// kAttn: 1024 blocks x 256 thr.  Wave per (h,q); 2 lanes per k, 16 c each.
// (r13 version — Dt/SFK from L2, measured 6.5us.)
__global__ void kAttn(const float* __restrict__ Dt, const void* __restrict__ maskp,
                      const float* __restrict__ SFK, float* __restrict__ ctx,
                      float* __restrict__ attnp, int fill) {
    __shared__ float aws[4][32];
    int vb = blockIdx.x, t = threadIdx.x;
    if (fill) ((float4*)attnp)[vb * 256 + t] = make_float4(1.f, 1.f, 1.f, 1.f);
    int qb = vb & 63, h = (vb >> 6) & 7, b = vb >> 9;
    int wave = t >> 6, l = t & 63;
    int q = qb * 4 + wave;
    int half = l & 1, klo = l >> 1;
    int g_q = q & 3;
    int i_q = h * 32 + (q >> 3);
    bool up_q = (q & 4) == 0;
    int ak = klo & 3;
    bool up_k = (klo & 4) == 0;

    bool mbytes = sniff_mask_bytes((const unsigned int*)maskp);

    float sq[16];
    const float* Db = Dt + ((b * 4 + g_q) * 4 + ak) * 32 + half * 16;
#pragma unroll
    for (int j = 0; j < 16; ++j) {
        int cc = half * 2 + (j >> 3);
        int row = g_q * 64 + 30 + cc;
        bool vq = up_q ? (i_q >= 256 - row) : (i_q <= 255 - row);
        sq[j] = vq ? Db[j] : 0.f;
    }

    float A[16];
#pragma unroll
    for (int j = 0; j < 16; ++j) A[j] = 0.f;

    int qrow = (b * 256 + q) * 256;
    for (int r = 0; r < 8; ++r) {
        int k = r * 32 + klo;
        bool masked = mbytes ? (((const unsigned char*)maskp)[qrow + k] != 0)
                             : (((const int*)maskp)[qrow + k] != 0);
        if (masked) {
#pragma unroll
            for (int j = 0; j < 16; ++j) A[j] += 0.03125f;
            continue;
        }
        int i_k = h * 32 + (k >> 3);
        float s[16];
        float mx = -1e30f;
#pragma unroll
        for (int j = 0; j < 16; ++j) {
            int cc = half * 2 + (j >> 3);
            int row = ak * 64 + 30 + cc;
            bool vk = up_k ? (i_k >= 256 - row) : (i_k <= 255 - row);
            s[j] = vk ? sq[j] : 0.f;
            mx = fmaxf(mx, s[j]);
        }
        mx = fmaxf(mx, __shfl_xor(mx, 1));
        float den = 0.f;
#pragma unroll
        for (int j = 0; j < 16; ++j) { s[j] = __expf(s[j] - mx); den += s[j]; }
        den += __shfl_xor(den, 1);
        float inv = 1.f / den;
#pragma unroll
        for (int j = 0; j < 16; ++j) A[j] += s[j] * inv;
    }

#pragma unroll
    for (int off = 2; off < 64; off <<= 1) {
#pragma unroll
        for (int j = 0; j < 16; ++j) A[j] += __shfl_xor(A[j], off);
    }

    float* aw = aws[wave];
    if (l < 2) {
#pragma unroll
        for (int j = 0; j < 16; ++j) aw[l * 16 + j] = A[j];
    }
    float acc = 0.f;
    const float* S = SFK + b * 2048;
#pragma unroll
    for (int c = 0; c < 32; ++c) acc += aw[c] * S[c * 64 + l];
    ctx[(b * 256 + q) * 512 + h * 64 + l] = acc;
}

// kG4LN: outer-product Wo GEMM + bias + residual + LayerNorm, fused.
// 128 blocks x 512 thr; block = 4 output rows.  (r9 version, 8.8us warm.)
__global__ __launch_bounds__(512) void kG4LN(
    const float* __restrict__ ctx, const float* __restrict__ Wo,
    const float* __restrict__ bo, const float* __restrict__ Qin,
    const float* __restrict__ gamma, const float* __restrict__ beta,
    float* __restrict__ out)
{
    __shared__ float  Cl[4][512];
    __shared__ float4 red4[8][4][64];
    __shared__ float  red2[8][2];

    int t = threadIdx.x, r0 = blockIdx.x * 4;
    int w = t >> 6, l = t & 63;

    ((float4*)Cl)[t] = ((const float4*)&ctx[r0 * 512])[t];
    __syncthreads();

    const float4* WoV = (const float4*)Wo;
    const float4* pA = WoV + (size_t)(w * 64) * 128 + l;
    const float4* pB = pA + 64;
    float4 a0A = {0,0,0,0}, a1A = {0,0,0,0}, a2A = {0,0,0,0}, a3A = {0,0,0,0};
    float4 a0B = {0,0,0,0}, a1B = {0,0,0,0}, a2B = {0,0,0,0}, a3B = {0,0,0,0};
    int m0 = w * 64;
    float4 wA = pA[0], wB = pB[0];
#pragma unroll 4
    for (int mm = 0; mm < 63; ++mm) {
        float4 nA = pA[(mm + 1) * 128];
        float4 nB = pB[(mm + 1) * 128];
        float s0 = Cl[0][m0 + mm], s1 = Cl[1][m0 + mm];
        float s2 = Cl[2][m0 + mm], s3 = Cl[3][m0 + mm];
        FMA4(a0A, s0, wA); FMA4(a1A, s1, wA); FMA4(a2A, s2, wA); FMA4(a3A, s3, wA);
        FMA4(a0B, s0, wB); FMA4(a1B, s1, wB); FMA4(a2B, s2, wB); FMA4(a3B, s3, wB);
        wA = nA; wB = nB;
    }
    {
        float s0 = Cl[0][m0 + 63], s1 = Cl[1][m0 + 63];
        float s2 = Cl[2][m0 + 63], s3 = Cl[3][m0 + 63];
        FMA4(a0A, s0, wA); FMA4(a1A, s1, wA); FMA4(a2A, s2, wA); FMA4(a3A, s3, wA);
        FMA4(a0B, s0, wB); FMA4(a1B, s1, wB); FMA4(a2B, s2, wB); FMA4(a3B, s3, wB);
    }

    red4[w][0][l] = a0A; red4[w][1][l] = a1A; red4[w][2][l] = a2A; red4[w][3][l] = a3A;
    __syncthreads();
    if (t < 256) {
        int r = t >> 6, c4 = t & 63;
        float4 s = red4[0][r][c4];
#pragma unroll
        for (int w2 = 1; w2 < 8; ++w2) {
            float4 v = red4[w2][r][c4];
            s.x += v.x; s.y += v.y; s.z += v.z; s.w += v.w;
        }
        float4 bb = ((const float4*)bo)[c4];
        float4 qq = ((const float4*)Qin)[(r0 + r) * 128 + c4];
        s.x += bb.x + qq.x; s.y += bb.y + qq.y;
        s.z += bb.z + qq.z; s.w += bb.w + qq.w;
        *(float4*)&Cl[r][c4 * 4] = s;
    }
    __syncthreads();
    red4[w][0][l] = a0B; red4[w][1][l] = a1B; red4[w][2][l] = a2B; red4[w][3][l] = a3B;
    __syncthreads();
    if (t < 256) {
        int r = t >> 6, c4 = t & 63;
        float4 s = red4[0][r][c4];
#pragma unroll
        for (int w2 = 1; w2 < 8; ++w2) {
            float4 v = red4[w2][r][c4];
            s.x += v.x; s.y += v.y; s.z += v.z; s.w += v.w;
        }
        float4 bb = ((const float4*)bo)[64 + c4];
        float4 qq = ((const float4*)Qin)[(r0 + r) * 128 + 64 + c4];
        s.x += bb.x + qq.x; s.y += bb.y + qq.y;
        s.z += bb.z + qq.z; s.w += bb.w + qq.w;
        *(float4*)&Cl[r][256 + c4 * 4] = s;
    }
    __syncthreads();

    int r = t >> 7, c = t & 127;
    float v0 = Cl[r][c], v1 = Cl[r][c + 128], v2 = Cl[r][c + 256], v3 = Cl[r][c + 384];
    float s1 = v0 + v1 + v2 + v3;
    float s2 = v0 * v0 + v1 * v1 + v2 * v2 + v3 * v3;
#pragma unroll
    for (int off = 1; off < 64; off <<= 1) {
        s1 += __shfl_xor(s1, off);
        s2 += __shfl_xor(s2, off);
    }
    if (l == 0) { red2[w][0] = s1; red2[w][1] = s2; }
    __syncthreads();
    float tot1 = red2[2 * r][0] + red2[2 * r + 1][0];
    float tot2 = red2[2 * r][1] + red2[2 * r + 1][1];
    float mu = tot1 * (1.f / 512.f);
    float var = tot2 * (1.f / 512.f) - mu * mu;
    float rs = rsqrtf(var + LN_EPS);
    float* op = out + (r0 + r) * 512;
    op[c]       = (v0 - mu) * rs * gamma[c]       + beta[c];
    op[c + 128] = (v1 - mu) * rs * gamma[c + 128] + beta[c + 128];
    op[c + 256] = (v2 - mu) * rs * gamma[c + 256] + beta[c + 256];
    op[c + 384] = (v3 - mu) * rs * gamma[c + 384] + beta[c + 384];
}

// plan-B only: restore attn_out region (which hosted scratch) to 1.0
__global__ void k5_fill(float* __restrict__ p, int n) {
    int i = (blockIdx.x * 256 + threadIdx.x) * 4;
    float4 one = make_float4(1.f, 1.f, 1.f, 1.f);
    for (; i < n; i += gridDim.x * 256 * 4) *(float4*)(p + i) = one;
}

extern "C" void kernel_launch(void* const* d_in, const int* in_sizes, int n_in,
                              void* d_out, int out_size, void* d_ws, size_t ws_size,
                              hipStream_t stream) {
    (void)in_sizes; (void)n_in; (void)out_size;
    const float* Qin  = (const float*)d_in[0];
    const float* Kin  = (const float*)d_in[1];
    const void*  mask = d_in[3];
    const float* WQ   = (const float*)d_in[4];
    const float* bQ   = (const float*)d_in[5];
    const float* WK   = (const float*)d_in[6];
    const float* bK   = (const float*)d_in[7];
    const float* Wo   = (const float*)d_in[10];
    const float* bo   = (const float*)d_in[11];
    const float* gamma= (const float*)d_in[12];
    const float* beta = (const float*)d_in[13];

    float* out   = (float*)d_out;
    float* attnp = out + 262144;                  // 1,048,576 floats (output 1)

    const size_t NEED = 791552ull * sizeof(float);
    int fill;
    float *Ppart, *Dt, *SFK, *ctx;
    if (ws_size >= NEED) {                        // plan A
        float* ws = (float*)d_ws;
        Ppart = ws;                               // 524288 (16 x 32768)
        Dt    = ws + 524288;                      // 1024
        SFK   = ws + 525312;                      // 4096
        ctx   = ws + 529408;                      // 262144
        fill = 1;
    } else {                                      // plan B (inside attn_out)
        Ppart = attnp;                            // [0, 524288)
        Dt    = attnp + 524288;                   // [524288, 525312)
        SFK   = attnp + 525312;                   // [525312, 529408)
        ctx   = attnp + 786432;                   // [786432, 1048576)
        fill = 0;
    }

    kAo_proj_part<<<dim3(64),   dim3(512), 0, stream>>>(Qin, Kin, WQ, WK, Ppart);
    kBC_dtab_sfk <<<dim3(48),   dim3(256), 0, stream>>>(Ppart, bQ, bK, Dt, SFK);
    kAttn        <<<dim3(1024), dim3(256), 0, stream>>>(Dt, mask, SFK, ctx, attnp, fill);
    kG4LN        <<<dim3(128),  dim3(512), 0, stream>>>(ctx, Wo, bo, Qin, gamma, beta, out);
    if (!fill) k5_fill<<<dim3(256), dim3(256), 0, stream>>>(attnp, 1048576);
}